// Round 6
// baseline (28.911 us; speedup 1.0000x reference)
//
#include <hip/hip_runtime.h>

// Problem constants (match reference: B=8192, S=7, C=30)
#define YB     8192
#define YS     7
#define YC     30
#define NCELLS (YB * YS * YS)      // 401408
#define WCELLS 64                  // cells per wave (one per lane)
#define BLOCK  256                 // 4 waves per block
#define CPB    (4 * WCELLS)        // 256 cells per block
#define NBLK   (NCELLS / CPB)      // 1568, divides exactly
#define NPART  (NCELLS / WCELLS)   // 6272 partials (one per wave)

__device__ __forceinline__ float iou_quirk(float cx1, float cy1, float w1, float h1,
                                           float cx2, float cy2, float w2, float h2) {
    // Faithful replica of reference _iou, including inter/area1 + area2 - inter quirk.
    float area1 = w1 * h1;
    float area2 = w2 * h2;
    float max_left   = fmaxf(cx1 - w1 * 0.5f, cx2 - w2 * 0.5f);
    float min_right  = fminf(cx1 + w1 * 0.5f, cx2 + w2 * 0.5f);
    float max_top    = fmaxf(cy1 - h1 * 0.5f, cy2 - h2 * 0.5f);
    float min_bottom = fminf(cy1 + h1 * 0.5f, cy2 + h2 * 0.5f);
    float inter = (min_right - max_left) * (min_bottom - max_top);
    bool overlap = (max_left < min_right) && (max_top < min_bottom);
    return overlap ? (inter / area1 + area2 - inter) : 0.0f;
}

__global__ __launch_bounds__(BLOCK) void yolo_partial_kernel(const float* __restrict__ preds,
                                                             const float* __restrict__ labels,
                                                             float* __restrict__ partial) {
    // Per-wave private LDS tiles: no __syncthreads in this kernel at all.
    // 4 waves x 2 inputs x 1920 floats = 61440 B -> 2 blocks/CU, 16 waves/CU.
    __shared__ float lds[4][2][WCELLS * YC];

    const int tid  = threadIdx.x;
    const int lane = tid & 63;
    const int w    = tid >> 6;

    const long cell0 = (long)blockIdx.x * CPB + (long)w * WCELLS;
    const float4* gp = (const float4*)(preds  + cell0 * YC);   // 7680B-aligned
    const float4* gl = (const float4*)(labels + cell0 * YC);
    float* sp = &lds[w][0][0];
    float* sl = &lds[w][1][0];
    float4* sp4 = (float4*)sp;
    float4* sl4 = (float4*)sl;
    const int NV = WCELLS * YC / 4;   // 480 float4 per input per wave

    // Wave-private staging, global -> LDS direct. Each iteration writes a
    // wave-uniform LDS base + lane*16 (linear dest, rule-compliant).
#if defined(__has_builtin) && __has_builtin(__builtin_amdgcn_global_load_lds)
    typedef const __attribute__((address_space(1))) void* as1_t;
    typedef __attribute__((address_space(3))) void* as3_t;
    for (int i = lane; i < NV; i += 64)
        __builtin_amdgcn_global_load_lds((as1_t)(gp + i), (as3_t)(sp4 + i), 16, 0, 0);
    for (int i = lane; i < NV; i += 64)
        __builtin_amdgcn_global_load_lds((as1_t)(gl + i), (as3_t)(sl4 + i), 16, 0, 0);
    // vmcnt is per-wave: wait only for OUR loads; no block barrier needed.
    asm volatile("s_waitcnt vmcnt(0)" ::: "memory");
    __builtin_amdgcn_sched_barrier(0);
#else
    for (int i = lane; i < NV; i += 64) sp4[i] = gp[i];
    for (int i = lane; i < NV; i += 64) sl4[i] = gl[i];
    asm volatile("s_waitcnt vmcnt(0) lgkmcnt(0)" ::: "memory");
    __builtin_amdgcn_sched_barrier(0);
#endif

    // Each lane processes one cell from this wave's LDS tile.
    const float2* p2 = (const float2*)(sp + lane * YC);   // 8B-aligned (120B stride)
    const float2* l2 = (const float2*)(sl + lane * YC);

    float pv[10], lv[10];
    #pragma unroll
    for (int i = 0; i < 5; ++i) {
        float2 a = p2[i]; pv[2 * i] = a.x; pv[2 * i + 1] = a.y;
        float2 b = l2[i]; lv[2 * i] = b.x; lv[2 * i + 1] = b.y;
    }
    float loss_cls = 0.0f;
    #pragma unroll
    for (int i = 5; i < 15; ++i) {
        float2 a = p2[i], b = l2[i];
        float dx = a.x - b.x, dy = a.y - b.y;
        loss_cls += dx * dx + dy * dy;
    }

    float iou1 = iou_quirk(pv[0], pv[1], pv[2], pv[3], lv[0], lv[1], lv[2], lv[3]);
    float iou2 = iou_quirk(pv[5], pv[6], pv[7], pv[8], lv[5], lv[6], lv[7], lv[8]);
    bool resp1 = iou1 > iou2;

    float dx1 = pv[0] - lv[0], dy1 = pv[1] - lv[1];
    float xy1 = dx1 * dx1 + dy1 * dy1;
    float dx2 = pv[5] - lv[5], dy2 = pv[6] - lv[6];
    float xy2 = dx2 * dx2 + dy2 * dy2;

    float sw1 = sqrtf(pv[2]) - sqrtf(lv[2]), sh1 = sqrtf(pv[3]) - sqrtf(lv[3]);
    float wh1 = sw1 * sw1 + sh1 * sh1;
    float sw2 = sqrtf(pv[7]) - sqrtf(lv[7]), sh2 = sqrtf(pv[8]) - sqrtf(lv[8]);
    float wh2 = sw2 * sw2 + sh2 * sh2;

    float d1 = pv[4] - iou1, d2 = pv[9] - iou2;
    float e1 = d1 * d1, e2 = d2 * d2;

    float loss_xy = 5.0f * (resp1 ? xy1 : xy2);
    float loss_wh = resp1 ? wh1 : wh2;
    float loss_obj = resp1 ? e1 : e2;
    float loss_noobj_objcell = 0.5f * (resp1 ? e2 : e1);

    float obj_cell = loss_xy + loss_wh + loss_obj + loss_noobj_objcell + loss_cls;
    float noobj_cell = 0.5f * (pv[4] * pv[4] + pv[9] * pv[9]);

    // labels[...,4] is exactly 0.0 or 1.0
    float v = (lv[4] == 1.0f) ? obj_cell : noobj_cell;

    // Deterministic wave64 shuffle-tree reduction; one partial per wave.
    for (int off = 32; off > 0; off >>= 1) v += __shfl_down(v, off);
    if (lane == 0) partial[blockIdx.x * 4 + w] = v;
}

__global__ __launch_bounds__(BLOCK) void yolo_final_kernel(const float* __restrict__ partial,
                                                           float* __restrict__ out) {
    __shared__ double w[BLOCK / 64];
    double s = 0.0;
    for (int i = threadIdx.x; i < NPART; i += BLOCK) s += (double)partial[i];
    for (int off = 32; off > 0; off >>= 1) s += __shfl_down(s, off);
    const int lane = threadIdx.x & 63, wid = threadIdx.x >> 6;
    if (lane == 0) w[wid] = s;
    __syncthreads();
    if (threadIdx.x == 0) out[0] = (float)((w[0] + w[1] + w[2] + w[3]) / (double)YB);
}

extern "C" void kernel_launch(void* const* d_in, const int* in_sizes, int n_in,
                              void* d_out, int out_size, void* d_ws, size_t ws_size,
                              hipStream_t stream) {
    const float* preds  = (const float*)d_in[0];
    const float* labels = (const float*)d_in[1];
    float* out = (float*)d_out;
    float* partial = (float*)d_ws;   // needs NPART*4 = 25088 bytes

    yolo_partial_kernel<<<NBLK, BLOCK, 0, stream>>>(preds, labels, partial);
    yolo_final_kernel<<<1, BLOCK, 0, stream>>>(partial, out);
}

// Round 8
// 25.275 us; speedup vs baseline: 1.1439x; 1.1439x over previous
//
#include <hip/hip_runtime.h>

// Problem constants (match reference: B=8192, S=7, C=30)
#define YB      8192
#define YS      7
#define YC      30
#define NCELLS  (YB * YS * YS)        // 401408
#define TCELLS  32                    // cells per wave-tile
#define TBYTES  (TCELLS * YC * 4)     // 3840 B per array per tile
#define TFLOATS (TCELLS * YC)         // 960 floats
#define NTILES  (NCELLS / TCELLS)     // 12544, divides exactly
#define BLOCK   256
#define GRID    512                   // 2 blocks/CU exactly
#define NWAVES  (GRID * 4)            // 2048 waves, 6-7 tiles each

__device__ __forceinline__ float iou_quirk(float cx1, float cy1, float w1, float h1,
                                           float cx2, float cy2, float w2, float h2) {
    // Faithful replica of reference _iou, including inter/area1 + area2 - inter quirk.
    float area1 = w1 * h1;
    float area2 = w2 * h2;
    float max_left   = fmaxf(cx1 - w1 * 0.5f, cx2 - w2 * 0.5f);
    float min_right  = fminf(cx1 + w1 * 0.5f, cx2 + w2 * 0.5f);
    float max_top    = fmaxf(cy1 - h1 * 0.5f, cy2 - h2 * 0.5f);
    float min_bottom = fminf(cy1 + h1 * 0.5f, cy2 + h2 * 0.5f);
    float inter = (min_right - max_left) * (min_bottom - max_top);
    bool overlap = (max_left < min_right) && (max_top < min_bottom);
    return overlap ? (inter / area1 + area2 - inter) : 0.0f;
}

// Per-lane cell loss from a staged 32-cell LDS tile (lanes >= TCELLS contribute 0).
__device__ __forceinline__ float cell_loss(const float* __restrict__ sp,
                                           const float* __restrict__ sl, int lane) {
    if (lane >= TCELLS) return 0.0f;
    // Cell base = lane*120 B (8B-aligned) -> float2. Stride 30 floats -> 2-way
    // bank alias per wave = free (m136).
    const float2* p2 = (const float2*)(sp + lane * YC);
    const float2* l2 = (const float2*)(sl + lane * YC);

    float pv[10], lv[10];
    #pragma unroll
    for (int i = 0; i < 5; ++i) {
        float2 a = p2[i]; pv[2 * i] = a.x; pv[2 * i + 1] = a.y;
        float2 b = l2[i]; lv[2 * i] = b.x; lv[2 * i + 1] = b.y;
    }
    float loss_cls = 0.0f;
    #pragma unroll
    for (int i = 5; i < 15; ++i) {
        float2 a = p2[i], b = l2[i];
        float dx = a.x - b.x, dy = a.y - b.y;
        loss_cls += dx * dx + dy * dy;
    }

    float iou1 = iou_quirk(pv[0], pv[1], pv[2], pv[3], lv[0], lv[1], lv[2], lv[3]);
    float iou2 = iou_quirk(pv[5], pv[6], pv[7], pv[8], lv[5], lv[6], lv[7], lv[8]);
    bool resp1 = iou1 > iou2;

    float dx1 = pv[0] - lv[0], dy1 = pv[1] - lv[1];
    float xy1 = dx1 * dx1 + dy1 * dy1;
    float dx2 = pv[5] - lv[5], dy2 = pv[6] - lv[6];
    float xy2 = dx2 * dx2 + dy2 * dy2;

    float sw1 = sqrtf(pv[2]) - sqrtf(lv[2]), sh1 = sqrtf(pv[3]) - sqrtf(lv[3]);
    float wh1 = sw1 * sw1 + sh1 * sh1;
    float sw2 = sqrtf(pv[7]) - sqrtf(lv[7]), sh2 = sqrtf(pv[8]) - sqrtf(lv[8]);
    float wh2 = sw2 * sw2 + sh2 * sh2;

    float d1 = pv[4] - iou1, d2 = pv[9] - iou2;
    float e1 = d1 * d1, e2 = d2 * d2;

    float obj_cell = 5.0f * (resp1 ? xy1 : xy2)
                   + (resp1 ? wh1 : wh2)
                   + (resp1 ? e1 : e2)
                   + 0.5f * (resp1 ? e2 : e1)
                   + loss_cls;
    float noobj_cell = 0.5f * (pv[4] * pv[4] + pv[9] * pv[9]);

    // labels[...,4] is exactly 0.0 or 1.0
    return (lv[4] == 1.0f) ? obj_cell : noobj_cell;
}

__global__ __launch_bounds__(BLOCK) void yolo_partial_kernel(const float* __restrict__ preds,
                                                             const float* __restrict__ labels,
                                                             float* __restrict__ partial) {
    // Per-wave private double-buffered tiles. NO __syncthreads anywhere.
    // [wave][buf][array][floats] = 4*2*2*960*4 = 61440 B -> 2 blocks/CU, 8 waves/CU.
    __shared__ float lds[4][2][2][TFLOATS];

    const int tid  = threadIdx.x;
    const int lane = tid & 63;
    const int w    = tid >> 6;
    const int wave_id = blockIdx.x * 4 + w;

    float acc = 0.0f;

#if defined(__has_builtin) && __has_builtin(__builtin_amdgcn_global_load_lds)
    typedef const __attribute__((address_space(1))) char* g_t;
    typedef __attribute__((address_space(3))) char* s_t;

    // Stage one 3840-B array-tile using ONLY HW-verified widths:
    // 3 x 16B (3072 B) + 3 x 4B (768 B) per lane. Linear LDS dest
    // (wave-uniform base + lane*size per instruction). 6 VMEM ops.
    #define STAGE_ARR(gbase, sbase)                                                        \
        do {                                                                               \
            __builtin_amdgcn_global_load_lds((g_t)((gbase) + lane * 16),                   \
                                             (s_t)((sbase) + lane * 16), 16, 0, 0);        \
            __builtin_amdgcn_global_load_lds((g_t)((gbase) + 1024 + lane * 16),            \
                                             (s_t)((sbase) + 1024 + lane * 16), 16, 0, 0); \
            __builtin_amdgcn_global_load_lds((g_t)((gbase) + 2048 + lane * 16),            \
                                             (s_t)((sbase) + 2048 + lane * 16), 16, 0, 0); \
            __builtin_amdgcn_global_load_lds((g_t)((gbase) + 3072 + lane * 4),             \
                                             (s_t)((sbase) + 3072 + lane * 4), 4, 0, 0);   \
            __builtin_amdgcn_global_load_lds((g_t)((gbase) + 3328 + lane * 4),             \
                                             (s_t)((sbase) + 3328 + lane * 4), 4, 0, 0);   \
            __builtin_amdgcn_global_load_lds((g_t)((gbase) + 3584 + lane * 4),             \
                                             (s_t)((sbase) + 3584 + lane * 4), 4, 0, 0);   \
        } while (0)

    // 12 VMEM instructions per tile (6 per array x 2 arrays).
    #define STAGE_TILE(tile, b)                                                            \
        do {                                                                               \
            const char* gp_ = (const char*)preds  + (size_t)(tile) * TBYTES;               \
            const char* gl_ = (const char*)labels + (size_t)(tile) * TBYTES;               \
            STAGE_ARR(gp_, (char*)&lds[w][(b)][0][0]);                                     \
            STAGE_ARR(gl_, (char*)&lds[w][(b)][1][0]);                                     \
        } while (0)

    int t = wave_id;          // always < NTILES (2048 <= 12544)
    int buf = 0;
    STAGE_TILE(t, 0);

    // Steady state: stage next tile, wait only for the CURRENT tile's 12
    // oldest loads (vmcnt decrements oldest-first, m135), compute, flip.
    for (;;) {
        const int tn = t + NWAVES;
        if (tn >= NTILES) break;                 // last tile handled in epilogue
        STAGE_TILE(tn, buf ^ 1);
        asm volatile("s_waitcnt vmcnt(12)" ::: "memory");
        __builtin_amdgcn_sched_barrier(0);
        acc += cell_loss(&lds[w][buf][0][0], &lds[w][buf][1][0], lane);
        buf ^= 1;
        t = tn;
    }
    // Epilogue: drain and compute the final tile.
    asm volatile("s_waitcnt vmcnt(0)" ::: "memory");
    __builtin_amdgcn_sched_barrier(0);
    acc += cell_loss(&lds[w][buf][0][0], &lds[w][buf][1][0], lane);

    #undef STAGE_TILE
    #undef STAGE_ARR
#else
    // Fallback: register staging, unpipelined.
    for (int t = wave_id, buf = 0; t < NTILES; t += NWAVES, buf ^= 1) {
        const float4* gp = (const float4*)((const char*)preds  + (size_t)t * TBYTES);
        const float4* gl = (const float4*)((const char*)labels + (size_t)t * TBYTES);
        float4* sp4 = (float4*)&lds[w][buf][0][0];
        float4* sl4 = (float4*)&lds[w][buf][1][0];
        for (int i = lane; i < TFLOATS / 4; i += 64) { sp4[i] = gp[i]; sl4[i] = gl[i]; }
        asm volatile("s_waitcnt vmcnt(0) lgkmcnt(0)" ::: "memory");
        __builtin_amdgcn_sched_barrier(0);
        acc += cell_loss(&lds[w][buf][0][0], &lds[w][buf][1][0], lane);
    }
#endif

    // Deterministic wave64 shuffle-tree reduction; one partial per wave.
    for (int off = 32; off > 0; off >>= 1) acc += __shfl_down(acc, off);
    if (lane == 0) partial[wave_id] = acc;
}

__global__ __launch_bounds__(BLOCK) void yolo_final_kernel(const float* __restrict__ partial,
                                                           float* __restrict__ out) {
    __shared__ double w[BLOCK / 64];
    double s = 0.0;
    for (int i = threadIdx.x; i < NWAVES; i += BLOCK) s += (double)partial[i];
    for (int off = 32; off > 0; off >>= 1) s += __shfl_down(s, off);
    const int lane = threadIdx.x & 63, wid = threadIdx.x >> 6;
    if (lane == 0) w[wid] = s;
    __syncthreads();
    if (threadIdx.x == 0) out[0] = (float)((w[0] + w[1] + w[2] + w[3]) / (double)YB);
}

extern "C" void kernel_launch(void* const* d_in, const int* in_sizes, int n_in,
                              void* d_out, int out_size, void* d_ws, size_t ws_size,
                              hipStream_t stream) {
    const float* preds  = (const float*)d_in[0];
    const float* labels = (const float*)d_in[1];
    float* out = (float*)d_out;
    float* partial = (float*)d_ws;   // needs NWAVES*4 = 8192 bytes

    yolo_partial_kernel<<<GRID, BLOCK, 0, stream>>>(preds, labels, partial);
    yolo_final_kernel<<<1, BLOCK, 0, stream>>>(partial, out);
}